// Round 10
// baseline (3838.864 us; speedup 1.0000x reference)
//
#include <hip/hip_runtime.h>
#include <math.h>
#include <stdint.h>

#define D512 512
#define SC_E (2.0f / 131072.0f)

typedef __attribute__((ext_vector_type(8))) __bf16 bf16x8;
typedef __attribute__((ext_vector_type(4))) float f32x4;
#define MFMA(a,b,c) __builtin_amdgcn_mfma_f32_16x16x32_bf16(a,b,c,0,0,0)

__device__ __forceinline__ float sigmoidf_(float z){ return 1.0f/(1.0f+expf(-z)); }
__device__ __forceinline__ float siluf_(float z){ return z/(1.0f+expf(-z)); }
__device__ __forceinline__ float dsiluf_(float z){ float s=1.0f/(1.0f+expf(-z)); return s*(1.0f+z*(1.0f-s)); }

__device__ __forceinline__ unsigned short f2bf(float x){
  union { float f; unsigned u; } c; c.f = x;
  unsigned r = (c.u + 0x7fffu + ((c.u >> 16) & 1u)) >> 16;
  return (unsigned short)r;
}
__device__ __forceinline__ float bf2f(unsigned short s){
  union { unsigned u; float f; } c; c.u = ((unsigned)s) << 16; return c.f;
}
__device__ __forceinline__ void split2(float x, unsigned short& h, unsigned short& l){
  h = f2bf(x); l = f2bf(x - bf2f(h));
}
__device__ __forceinline__ bf16x8 ldf(const unsigned short* p){ return *(const bf16x8*)p; }

// ---------- write-through comm stores (agent-scope relaxed atomics -> L3) ----------
// Producers write via these; consumers use plain cached loads, made safe by ONE
// acquire-inv per scan step. No release fences / wbl2 anywhere.
__device__ __forceinline__ void stc_u32(unsigned* p, unsigned v){
  __hip_atomic_store(p, v, __ATOMIC_RELAXED, __HIP_MEMORY_SCOPE_AGENT);
}
__device__ __forceinline__ void stc_u64(unsigned long long* p, unsigned long long v){
  __hip_atomic_store(p, v, __ATOMIC_RELAXED, __HIP_MEMORY_SCOPE_AGENT);
}
__device__ __forceinline__ void stc_us4(unsigned short* p, ushort4 v){
  union { ushort4 s; unsigned long long q; } u; u.s = v;
  stc_u64((unsigned long long*)p, u.q);
}
// Pair-packed bf16 store: lanes (2c,2c+1) hold adjacent columns; even lane stores
// one u32. All call sites have even-lane elements 4B-aligned.
__device__ __forceinline__ void stc_pair(unsigned short* p, unsigned short v){
  unsigned ov = (unsigned)__shfl_xor((int)(unsigned)v, 1, 64);
  if (!(threadIdx.x & 1))
    stc_u32((unsigned*)p, ((unsigned)v) | (ov << 16));
}

// ---------- hierarchical fence-free grid barrier (256 blocks) ----------
// 8 arrival counters on separate 256B-spaced lines (group = bid&7; 32 arrivals
// each); leader (bid<8) aggregates into a global counter, publishes per-group
// 'go'; peers poll only their go line. All relaxed agent-scope; __syncthreads
// drains vmcnt so WT stores are L3-visible before arrival. Monotonic -> no ABA.
// Layout: cnt[g]=bar[g*64]; go[g]=bar[512+g*64]; global=bar[1024].
__device__ __forceinline__ void gbar_h(unsigned* bar, int grp, bool leader, unsigned p){
  __syncthreads();
  if (threadIdx.x == 0){
    unsigned* cnt = bar + grp*64;
    unsigned* go  = bar + 512 + grp*64;
    unsigned* gl  = bar + 1024;
    __hip_atomic_fetch_add(cnt, 1u, __ATOMIC_RELAXED, __HIP_MEMORY_SCOPE_AGENT);
    if (leader){
      while (__hip_atomic_load(cnt, __ATOMIC_RELAXED, __HIP_MEMORY_SCOPE_AGENT) < 32u*p)
        __builtin_amdgcn_s_sleep(1);
      __hip_atomic_fetch_add(gl, 1u, __ATOMIC_RELAXED, __HIP_MEMORY_SCOPE_AGENT);
      while (__hip_atomic_load(gl, __ATOMIC_RELAXED, __HIP_MEMORY_SCOPE_AGENT) < 8u*p)
        __builtin_amdgcn_s_sleep(1);
      __hip_atomic_store(go, p, __ATOMIC_RELAXED, __HIP_MEMORY_SCOPE_AGENT);
    } else {
      while (__hip_atomic_load(go, __ATOMIC_RELAXED, __HIP_MEMORY_SCOPE_AGENT) < p)
        __builtin_amdgcn_s_sleep(2);
    }
  }
  __syncthreads();
  __atomic_signal_fence(__ATOMIC_ACQUIRE);  // compiler-only ordering
}

// ---------- MFMA 64x64 tile primitives (4 waves; pre/post GEMMs) ----------
// Verified layouts (learn_hip m89/m91/m120).
template<int KTOT>
__device__ __forceinline__ void tile_ss(const unsigned short* __restrict__ A, int lda,
                                        const unsigned short* __restrict__ B, int ldb,
                                        f32x4* acc){
  const int lane = threadIdx.x & 63, wave = threadIdx.x >> 6;
  const int kq = (lane >> 4) << 3;
  const size_t aoff = (size_t)(wave*16 + (lane & 15)) * lda + kq;
  const size_t boff0 = (size_t)(lane & 15) * ldb + kq;
#pragma unroll
  for (int k0 = 0; k0 < KTOT; k0 += 32){
    bf16x8 av = ldf(A + aoff + k0);
#pragma unroll
    for (int nn = 0; nn < 4; nn++){
      bf16x8 bv = ldf(B + boff0 + (size_t)(nn*16)*ldb + k0);
      acc[nn] = MFMA(av, bv, acc[nn]);
    }
  }
}

template<int KTOT>
__device__ __forceinline__ void tile_dd(const unsigned short* __restrict__ Ah, const unsigned short* __restrict__ Al, int lda,
                                        const unsigned short* __restrict__ Bh, const unsigned short* __restrict__ Bl, int ldb,
                                        f32x4* acc){
  const int lane = threadIdx.x & 63, wave = threadIdx.x >> 6;
  const int kq = (lane >> 4) << 3;
  const size_t aoff = (size_t)(wave*16 + (lane & 15)) * lda + kq;
  const size_t boff0 = (size_t)(lane & 15) * ldb + kq;
#pragma unroll
  for (int k0 = 0; k0 < KTOT; k0 += 32){
    bf16x8 ah = ldf(Ah + aoff + k0);
    bf16x8 al = ldf(Al + aoff + k0);
#pragma unroll
    for (int nn = 0; nn < 4; nn++){
      const size_t bo = boff0 + (size_t)(nn*16)*ldb + k0;
      bf16x8 bh = ldf(Bh + bo);
      bf16x8 bl = ldf(Bl + bo);
      acc[nn] = MFMA(ah, bh, acc[nn]);
      acc[nn] = MFMA(ah, bl, acc[nn]);
      acc[nn] = MFMA(al, bh, acc[nn]);
    }
  }
}

// ---------- sliced tile primitives (scan): 16 A-rows x 64 B-rows, 1 f32x4/thread ----
// 8-wave K-split: wave w4 = wave&3 picks B-cols, h = wave>>2 picks K-half (koff).
// Out: A_row = (lane>>4)*4 + r, B_col = w4*16 + (lane&15).
template<int KTOT>
__device__ __forceinline__ void slice_ss(const unsigned short* __restrict__ A16, int lda,
                                         const unsigned short* __restrict__ B64, int ldb,
                                         f32x4& acc, int koff){
  const int lane = threadIdx.x & 63, w4 = (threadIdx.x >> 6) & 3;
  const int kq = ((lane >> 4) << 3) + koff;
  const size_t aoff = (size_t)(lane & 15) * lda + kq;
  const size_t boff = (size_t)(w4*16 + (lane & 15)) * ldb + kq;
#pragma unroll
  for (int k0 = 0; k0 < KTOT; k0 += 32){
    bf16x8 av = ldf(A16 + aoff + k0);
    bf16x8 bv = ldf(B64 + boff + k0);
    acc = MFMA(av, bv, acc);
  }
}

template<int KTOT>
__device__ __forceinline__ void slice_dd(const unsigned short* __restrict__ Ah, const unsigned short* __restrict__ Al, int lda,
                                         const unsigned short* __restrict__ Bh, const unsigned short* __restrict__ Bl, int ldb,
                                         f32x4& acc, int koff){
  const int lane = threadIdx.x & 63, w4 = (threadIdx.x >> 6) & 3;
  const int kq = ((lane >> 4) << 3) + koff;
  const size_t aoff = (size_t)(lane & 15) * lda + kq;
  const size_t boff = (size_t)(w4*16 + (lane & 15)) * ldb + kq;
#pragma unroll
  for (int k0 = 0; k0 < KTOT; k0 += 32){
    bf16x8 ah = ldf(Ah + aoff + k0);
    bf16x8 al = ldf(Al + aoff + k0);
    bf16x8 bh = ldf(Bh + boff + k0);
    bf16x8 bl = ldf(Bl + boff + k0);
    acc = MFMA(ah, bh, acc);
    acc = MFMA(ah, bl, acc);
    acc = MFMA(al, bh, acc);
  }
}

// ---------- elementwise / pre kernels ----------
__global__ void rms_store_kernel(const float* __restrict__ x, const float* __restrict__ g,
                                 unsigned short* __restrict__ dstH){
  const size_t row = blockIdx.x; const int tid = threadIdx.x; // 128 thr
  const float4 xv = *(const float4*)(x + row * D512 + tid * 4);
  float ss = xv.x*xv.x + xv.y*xv.y + xv.z*xv.z + xv.w*xv.w;
  for (int o = 32; o > 0; o >>= 1) ss += __shfl_xor(ss, o, 64);
  __shared__ float w2[2];
  if ((tid & 63) == 0) w2[tid >> 6] = ss;
  __syncthreads();
  const float r = rsqrtf((w2[0] + w2[1]) * (1.0f / 512.0f) + 1.1920929e-07f);
  const float4 gv = *(const float4*)(g + tid * 4);
  ushort4 h;
  h.x = f2bf(xv.x*r*gv.x); h.y = f2bf(xv.y*r*gv.y); h.z = f2bf(xv.z*r*gv.z); h.w = f2bf(xv.w*r*gv.w);
  *(ushort4*)(dstH + row * D512 + tid * 4) = h;
}

__global__ void rms_retr_kernel(const float* __restrict__ x, const float* __restrict__ g,
                                unsigned short* __restrict__ dstH, unsigned short* __restrict__ dstL){
  const size_t row = blockIdx.x; const int tid = threadIdx.x; // 128 thr
  const float4 xv = *(const float4*)(x + row * D512 + tid * 4);
  float ss = xv.x*xv.x + xv.y*xv.y + xv.z*xv.z + xv.w*xv.w;
  for (int o = 32; o > 0; o >>= 1) ss += __shfl_xor(ss, o, 64);
  __shared__ float w2[2];
  if ((tid & 63) == 0) w2[tid >> 6] = ss;
  __syncthreads();
  const float r = rsqrtf((w2[0] + w2[1]) * (1.0f / 512.0f) + 1.1920929e-07f);
  const float4 gv = *(const float4*)(g + tid * 4);
  float v0 = xv.x*r*gv.x, v1 = xv.y*r*gv.y, v2 = xv.z*r*gv.z, v3 = xv.w*r*gv.w;
  ushort4 h, l;
  split2(v0, h.x, l.x); split2(v1, h.y, l.y); split2(v2, h.z, l.z); split2(v3, h.w, l.w);
  *(ushort4*)(dstH + row * D512 + tid * 4) = h;
  *(ushort4*)(dstL + row * D512 + tid * 4) = l;
}

__global__ void l2norm_split_kernel(float* __restrict__ buf,
                                    unsigned short* __restrict__ dstH, unsigned short* __restrict__ dstL){
  const size_t row = blockIdx.x; const int tid = threadIdx.x; // 128 thr
  float4 xv = *(const float4*)(buf + row * D512 + tid * 4);
  float ss = xv.x*xv.x + xv.y*xv.y + xv.z*xv.z + xv.w*xv.w;
  for (int o = 32; o > 0; o >>= 1) ss += __shfl_xor(ss, o, 64);
  __shared__ float w2[2];
  if ((tid & 63) == 0) w2[tid >> 6] = ss;
  __syncthreads();
  const float n = sqrtf(w2[0] + w2[1]);
  const float sc = 1.0f / fmaxf(n, 1e-12f);
  xv.x *= sc; xv.y *= sc; xv.z *= sc; xv.w *= sc;
  *(float4*)(buf + row * D512 + tid * 4) = xv;
  ushort4 h; h.x = f2bf(xv.x); h.y = f2bf(xv.y); h.z = f2bf(xv.z); h.w = f2bf(xv.w);
  *(ushort4*)(dstH + row * D512 + tid * 4) = h;
  if (dstL){
    ushort4 l;
    l.x = f2bf(xv.x - bf2f(h.x)); l.y = f2bf(xv.y - bf2f(h.y));
    l.z = f2bf(xv.z - bf2f(h.z)); l.w = f2bf(xv.w - bf2f(h.w));
    *(ushort4*)(dstL + row * D512 + tid * 4) = l;
  }
}

__global__ void cast_kernel(const float* __restrict__ src, unsigned short* __restrict__ dstH,
                            unsigned short* __restrict__ dstL, int n){
  int i = (blockIdx.x * 256 + threadIdx.x) * 4;
  if (i >= n) return;
  float4 v = *(const float4*)(src + i);
  ushort4 h; h.x = f2bf(v.x); h.y = f2bf(v.y); h.z = f2bf(v.z); h.w = f2bf(v.w);
  *(ushort4*)(dstH + i) = h;
  if (dstL){
    ushort4 l;
    l.x = f2bf(v.x - bf2f(h.x)); l.y = f2bf(v.y - bf2f(h.y));
    l.z = f2bf(v.z - bf2f(h.z)); l.w = f2bf(v.w - bf2f(h.w));
    *(ushort4*)(dstL + i) = l;
  }
}

// transpose fp32 [R][C] -> bf16 (single/split) [C][R]; grid(C/64, R/64, batches)
__global__ void trans_cast_kernel(const float* __restrict__ src, unsigned short* __restrict__ dstH,
                                  unsigned short* __restrict__ dstL, int R, int C,
                                  size_t sbs, size_t dbs){
  __shared__ float t[64][65];
  const int b = blockIdx.z;
  const float* s = src + (size_t)b * sbs;
  const int r0 = blockIdx.y * 64, c0 = blockIdx.x * 64;
  for (int i = threadIdx.x; i < 4096; i += 256){
    int rr = i >> 6, cc = i & 63;
    t[rr][cc] = s[(size_t)(r0 + rr) * C + c0 + cc];
  }
  __syncthreads();
  for (int i = threadIdx.x; i < 4096; i += 256){
    int cc = i >> 6, rr = i & 63;
    float v = t[rr][cc];
    size_t off = (size_t)b * dbs + (size_t)(c0 + cc) * R + r0 + rr;
    unsigned short h = f2bf(v);
    dstH[off] = h;
    if (dstL) dstL[off] = f2bf(v - bf2f(h));
  }
}

__global__ void chunk_mean_kernel(const float* __restrict__ x, float* __restrict__ cm){
  const int c = blockIdx.x, b = blockIdx.y, tid = threadIdx.x; // 128 threads
  const float* base = x + ((size_t)b * 4096 + (size_t)c * 64) * D512 + tid * 4;
  float4 s = {0,0,0,0};
  for (int r = 0; r < 64; r++){
    const float4 v = *(const float4*)(base + (size_t)r * D512);
    s.x += v.x; s.y += v.y; s.z += v.z; s.w += v.w;
  }
  const float inv = 1.0f / 64.0f;
  s.x *= inv; s.y *= inv; s.z *= inv; s.w *= inv;
  *(float4*)(cm + ((size_t)b * 64 + c) * D512 + tid * 4) = s;
}

// gates: single pass over the 3 gate matrices (all 4 batch chunk-means staged in
// LDS) -- r9's version re-read 3MB of weights once per batch (4x amplification).
__global__ void gates_kernel(const float* __restrict__ cm,
                             const float* __restrict__ Wgd, const float* __restrict__ bgd,
                             const float* __restrict__ Wgl, const float* __restrict__ bgl,
                             const float* __restrict__ Wgm, const float* __restrict__ bgm,
                             float* __restrict__ alpha, float* __restrict__ theta, float* __restrict__ eta){
  const int c = blockIdx.x, tid = threadIdx.x; // 256 threads
  __shared__ float cmsh[4][512];
#pragma unroll
  for (int b = 0; b < 4; b++)
    if (tid < 128)
      *(float4*)&cmsh[b][tid * 4] = *(const float4*)(cm + ((size_t)b * 64 + c) * D512 + tid * 4);
  __syncthreads();
  float s0 = 0.f, s1 = 0.f, s2 = 0.f;
  for (int j = tid; j < 512; j += 256){
    float d0[4], d1[4], d2[4];
#pragma unroll
    for (int b = 0; b < 4; b++){ d0[b] = bgd[j]; d1[b] = bgl[j]; d2[b] = bgm[j]; }
    const float* w0 = Wgd + (size_t)j * D512;
    const float* w1 = Wgl + (size_t)j * D512;
    const float* w2 = Wgm + (size_t)j * D512;
    for (int kk = 0; kk < 512; kk += 4){
      const float4 a = *(const float4*)(w0 + kk);
      const float4 e = *(const float4*)(w1 + kk);
      const float4 g = *(const float4*)(w2 + kk);
#pragma unroll
      for (int b = 0; b < 4; b++){
        const float4 cv = *(const float4*)&cmsh[b][kk];
        d0[b] += cv.x*a.x + cv.y*a.y + cv.z*a.z + cv.w*a.w;
        d1[b] += cv.x*e.x + cv.y*e.y + cv.z*e.z + cv.w*e.w;
        d2[b] += cv.x*g.x + cv.y*g.y + cv.z*g.z + cv.w*g.w;
      }
    }
#pragma unroll
    for (int b = 0; b < 4; b++){
      s0 += sigmoidf_(d0[b]); s1 += sigmoidf_(d1[b]); s2 += sigmoidf_(d2[b]);
    }
  }
  __shared__ float red[256];
  const float inv = 1.0f / 2048.0f;
  red[tid] = s0; __syncthreads();
  for (int o = 128; o > 0; o >>= 1){ if (tid < o) red[tid] += red[tid + o]; __syncthreads(); }
  if (tid == 0) alpha[c] = red[0] * inv * 0.01f;
  __syncthreads();
  red[tid] = s1; __syncthreads();
  for (int o = 128; o > 0; o >>= 1){ if (tid < o) red[tid] += red[tid + o]; __syncthreads(); }
  if (tid == 0) theta[c] = red[0] * inv * 0.1f;
  __syncthreads();
  red[tid] = s2; __syncthreads();
  for (int o = 128; o > 0; o >>= 1){ if (tid < o) red[tid] += red[tid + o]; __syncthreads(); }
  if (tid == 0) eta[c] = red[0] * inv * 0.9f;
}

// ---------- big MFMA GEMMs (NT: C[i,j] = sum_k A[i,k] B[j,k]) ----------
// blockIdx.x = ROW tile (multiple of 8) -> same-A-panel blocks co-XCD.
template<int MODE>
__global__ __launch_bounds__(256) void gemm_ss(const unsigned short* __restrict__ A,
                                               const unsigned short* __restrict__ B, size_t bzs,
                                               void* __restrict__ out){
  const int lane = threadIdx.x & 63, wave = threadIdx.x >> 6;
  const int er = wave*16 + ((lane >> 4) << 2), ec = lane & 15;
  const size_t row0 = (size_t)blockIdx.z * 4096 + (size_t)blockIdx.x * 64;
  const int n0 = blockIdx.y * 64;
  f32x4 acc[4] = {};
  tile_ss<512>(A + row0 * D512, D512, B + (size_t)blockIdx.z * bzs + (size_t)n0 * D512, D512, acc);
#pragma unroll
  for (int nn = 0; nn < 4; nn++)
#pragma unroll
    for (int r = 0; r < 4; r++){
      const size_t off = (row0 + er + r) * D512 + n0 + nn*16 + ec;
      float val = acc[nn][r];
      if (MODE == 0) ((unsigned short*)out)[off] = f2bf(val);
      else if (MODE == 1) ((float*)out)[off] = siluf_(val);
      else ((float*)out)[off] = val;
    }
}

template<int MODE>
__global__ __launch_bounds__(256) void gemm_dd(const unsigned short* __restrict__ Ah, const unsigned short* __restrict__ Al,
                                               const unsigned short* __restrict__ Bh, const unsigned short* __restrict__ Bl,
                                               float* __restrict__ out){
  const int lane = threadIdx.x & 63, wave = threadIdx.x >> 6;
  const int er = wave*16 + ((lane >> 4) << 2), ec = lane & 15;
  const size_t row0 = (size_t)blockIdx.x * 64;
  const int n0 = blockIdx.y * 64;
  f32x4 acc[4] = {};
  tile_dd<512>(Ah + row0 * D512, Al + row0 * D512, D512,
               Bh + (size_t)n0 * D512, Bl + (size_t)n0 * D512, D512, acc);
#pragma unroll
  for (int nn = 0; nn < 4; nn++)
#pragma unroll
    for (int r = 0; r < 4; r++){
      const size_t off = (row0 + er + r) * D512 + n0 + nn*16 + ec;
      out[off] = (MODE == 1) ? siluf_(acc[nn][r]) : acc[nn][r];
    }
}

// ---------- fused scan: 256 blocks x 512 threads (8 waves, K-split) ----------
// bid = s*64 + T (T = tile 0..63, s = 16-row slice 0..3). Waves 0-3 (h=0)
// accumulate K in [0,256); waves 4-7 (h=1) accumulate K in [256,512); LDS
// exchange merges partials; epilogues run on h=0 (where sp-carry + optimizer
// state live). Phase D: h=0 computes gW0, h=1 computes gW1 (no K-split needed).
// Doubles waves/SIMD (1->2) on all 256 CUs for L3-latency overlap at identical
// traffic (r8 lesson: never shrink the set of miss-issuing CUs).
struct ScanArgs {
  const unsigned short* kbH;
  const unsigned short* qbH; const unsigned short* qbL;
  unsigned short* W0bH; unsigned short* W0bL;
  unsigned short* hkbH; unsigned short* hkTbH;
  unsigned short* hqbH; unsigned short* hqbL;
  unsigned short* W1bH; unsigned short* W1bL;
  const float* v;
  unsigned short* ebH; unsigned short* eTbH;
  unsigned short* retH; unsigned short* retL;
  unsigned short* W1TbH; unsigned short* dpTbH;
  const float* alpha; const float* theta; const float* eta;
  const unsigned short* kTbH;
  const float* W0f; const float* W1f;
  unsigned* bar;
};

__global__ __launch_bounds__(512, 1) void scan_fused(ScanArgs P){
  const int bid = blockIdx.x;
  const int s = bid >> 6;
  const int T = bid & 63;
  const int grp = bid & 7;
  const bool leader = (bid < 8);
  const int tid = threadIdx.x;
  const int lane = tid & 63;
  const int wave = tid >> 6;           // 0..7
  const int w4 = wave & 3;
  const int h = wave >> 2;             // K-half / role
  const int ar = (lane >> 4) << 2;     // A-row base within 16-slice
  const int bc = w4*16 + (lane & 15);  // B-col within 64
  const int kq = (lane >> 4) << 3;
  const int koff = h * 256;

  __shared__ f32x4 red[4][64];

  // ---- D-role register state (h=0 threads): rows jx*64+s*16+ar+r, cols dx*64+bc ----
  const int jx = T >> 3, dx = T & 7;
  f32x4 w0r = {}, m0r = {}, w1r = {}, m1r = {};
  const size_t woff = (size_t)(jx*64 + s*16 + ar) * D512 + dx*64 + bc;
  if (h == 0){
#pragma unroll
    for (int r = 0; r < 4; r++){
      w0r[r] = P.W0f[woff + (size_t)r * D512];
      w1r[r] = P.W1f[woff + (size_t)r * D512];
    }
  }

  unsigned p = 0;
  for (int t = 0; t < 64; ++t){
    float4 sp = {0,0,0,0};   // a12 -> c1 carry (h=0 threads)

    // ---------------- phase A ----------------
    if (T < 32){
      // a12 (tile ib,jxa): hk[i][j], hkT[j][i], sp regs
      const int ib = T >> 3, jxa = T & 7;
      f32x4 acc = {};
      slice_ss<256>(P.kbH + ((size_t)ib*4096 + (size_t)t*64 + s*16) * D512, D512,
                    P.W0bH + (size_t)jxa*64 * D512, D512, acc, koff);
      if (h == 1) red[w4][lane] = acc;
      __syncthreads();
      if (h == 0){
        const f32x4 o = red[w4][lane];
        const int i0 = ib*64 + s*16 + ar;
        const int j  = jxa*64 + bc;
        ushort4 hv;
#pragma unroll
        for (int r = 0; r < 4; r++){
          const float pfull = acc[r] + o[r];
          const unsigned short hb = f2bf(siluf_(pfull));
          stc_pair(&P.hkbH[(size_t)(i0 + r) * D512 + j], hb);
          ((unsigned short*)&hv)[r] = hb;
          ((float*)&sp)[r] = dsiluf_(pfull);
        }
        stc_us4(&P.hkTbH[(size_t)j * 256 + i0], hv);
      }
    } else {
      // a3 (tile bt,nx): hq split
      const int u = T - 32, bt = u >> 3, nx = u & 7;
      const size_t ab = ((size_t)bt*4096 + (size_t)t*64 + s*16) * D512;
      f32x4 acc = {};
      slice_dd<256>(P.qbH + ab, P.qbL + ab, D512,
                    P.W0bH + (size_t)nx*64 * D512, P.W0bL + (size_t)nx*64 * D512, D512, acc, koff);
      if (h == 1) red[w4][lane] = acc;
      __syncthreads();
      if (h == 0){
        const f32x4 o = red[w4][lane];
        const int i0 = bt*64 + s*16 + ar;
        const int j  = nx*64 + bc;
#pragma unroll
        for (int r = 0; r < 4; r++){
          const float hq = siluf_(acc[r] + o[r]);
          unsigned short hh, ll; split2(hq, hh, ll);
          stc_pair(&P.hqbH[(size_t)(i0 + r) * D512 + j], hh);
          stc_pair(&P.hqbL[(size_t)(i0 + r) * D512 + j], ll);
        }
      }
    }
    ++p; gbar_h(P.bar, grp, leader, p);

    // ---------------- phase B ----------------
    if (T < 32){
      // b12 (tile ib,nx): e[i][m], eT[m][i]
      const int ib = T >> 3, nx = T & 7;
      f32x4 acc = {};
      slice_ss<256>(P.hkbH + (size_t)(ib*64 + s*16) * D512, D512,
                    P.W1bH + (size_t)nx*64 * D512, D512, acc, koff);
      if (h == 1) red[w4][lane] = acc;
      __syncthreads();
      if (h == 0){
        const f32x4 o = red[w4][lane];
        const int i0 = ib*64 + s*16 + ar;
        const int m  = nx*64 + bc;
        ushort4 ev;
#pragma unroll
        for (int r = 0; r < 4; r++){
          const size_t grow = (size_t)ib*4096 + (size_t)t*64 + s*16 + ar + r;
          const float vv = P.v[grow * D512 + m];
          const unsigned short eb = f2bf((acc[r] + o[r] - vv) * SC_E);
          stc_pair(&P.ebH[(size_t)(i0 + r) * D512 + m], eb);
          ((unsigned short*)&ev)[r] = eb;
        }
        stc_us4(&P.eTbH[(size_t)m * 256 + i0], ev);
      }
    } else {
      // b3 (tile bt,nx): ret split (plain cached stores; consumed post-scan)
      const int u = T - 32, bt = u >> 3, nx = u & 7;
      const size_t ab = (size_t)(bt*64 + s*16) * D512;
      f32x4 acc = {};
      slice_dd<256>(P.hqbH + ab, P.hqbL + ab, D512,
                    P.W1bH + (size_t)nx*64 * D512, P.W1bL + (size_t)nx*64 * D512, D512, acc, koff);
      if (h == 1) red[w4][lane] = acc;
      __syncthreads();
      if (h == 0){
        const f32x4 o = red[w4][lane];
#pragma unroll
        for (int r = 0; r < 4; r++){
          const size_t grow = (size_t)bt*4096 + (size_t)t*64 + s*16 + ar + r;
          unsigned short hh, ll; split2(acc[r] + o[r], hh, ll);
          const size_t off = grow * D512 + nx*64 + bc;
          P.retH[off] = hh; P.retL[off] = ll;
        }
      }
    }
    ++p; gbar_h(P.bar, grp, leader, p);

    // ---------------- phase C (c1 only; mom1 folded into D) ----------------
    if (T < 32){
      const int ib = T >> 3, jxa = T & 7;
      f32x4 acc = {};
      slice_ss<256>(P.ebH + (size_t)(ib*64 + s*16) * D512, D512,
                    P.W1TbH + (size_t)jxa*64 * D512, D512, acc, koff);
      if (h == 1) red[w4][lane] = acc;
      __syncthreads();
      if (h == 0){
        const f32x4 o = red[w4][lane];
        const int i0 = ib*64 + s*16 + ar;
        const int j  = jxa*64 + bc;
        ushort4 dv;
#pragma unroll
        for (int r = 0; r < 4; r++)
          ((unsigned short*)&dv)[r] = f2bf((acc[r] + o[r]) * ((const float*)&sp)[r]);
        stc_us4(&P.dpTbH[(size_t)j * 256 + i0], dv);
      }
    }
    ++p; gbar_h(P.bar, grp, leader, p);

    // ---------------- phase D (h=0: gW0; h=1: gW1; LDS handoff) ----------------
    {
      f32x4 g = {};
      if (h == 0){
        // gW0 = dpT @ kT (K=256)
        const unsigned short* A16 = P.dpTbH + (size_t)(jx*64 + s*16) * 256;
        const size_t aoff = (size_t)(lane & 15) * 256 + kq;
        const size_t brow = (size_t)(dx*64 + bc) * 4096;
#pragma unroll
        for (int k0 = 0; k0 < 256; k0 += 32){
          bf16x8 av = ldf(A16 + aoff + k0);
          const int pl = k0 >> 6;
          bf16x8 bv = ldf(P.kTbH + (size_t)pl * (512*4096) + brow + (size_t)t*64 + (k0 & 63) + kq);
          g = MFMA(av, bv, g);
        }
      } else {
        // gW1 tile: rows m=jx*64+s*16+ar+r, cols j=dx*64+bc, K=256
        slice_ss<256>(P.eTbH + (size_t)(jx*64 + s*16) * 256, 256,
                      P.hkTbH + (size_t)(dx*64) * 256, 256, g, 0);
        red[w4][lane] = g;
      }
      __syncthreads();
      if (h == 0){
        const f32x4 g1 = red[w4][lane];
        const float al = P.alpha[t], th = P.theta[t], et = P.eta[t];
        ushort4 tv;
#pragma unroll
        for (int r = 0; r < 4; r++){
          const size_t off = woff + (size_t)r * D512;
          m0r[r] = et * m0r[r] - th * g[r];
          w0r[r] = (1.0f - al) * w0r[r] + m0r[r];
          unsigned short hh, ll; split2(w0r[r], hh, ll);
          stc_pair(&P.W0bH[off], hh); stc_pair(&P.W0bL[off], ll);
          m1r[r] = et * m1r[r] - th * g1[r];
          w1r[r] = (1.0f - al) * w1r[r] + m1r[r];
          unsigned short h1, l1; split2(w1r[r], h1, l1);
          stc_pair(&P.W1bH[off], h1); stc_pair(&P.W1bL[off], l1);
          ((unsigned short*)&tv)[r] = h1;
        }
        // W1T[j][m0..m0+4) : contiguous u64 per thread
        stc_us4(&P.W1TbH[(size_t)(dx*64 + bc) * D512 + jx*64 + s*16 + ar], tv);
      }
    }
    ++p; gbar_h(P.bar, grp, leader, p);

    // One invalidate per step: all of step t's WT writes become safely readable
    // via plain cached loads throughout step t+1.
    __builtin_amdgcn_fence(__ATOMIC_ACQUIRE, "agent");
  }
}

// ---------------- launcher ----------------
extern "C" void kernel_launch(void* const* d_in, const int* in_sizes, int n_in,
                              void* d_out, int out_size, void* d_ws, size_t ws_size,
                              hipStream_t stream) {
  const float* x    = (const float*)d_in[0];
  const float* Mb   = (const float*)d_in[1];
  const float* memW = (const float*)d_in[2];
  const float* Wk   = (const float*)d_in[3];
  const float* Wv   = (const float*)d_in[4];
  const float* Wq   = (const float*)d_in[5];
  const float* Wout = (const float*)d_in[6];
  const float* Wgd  = (const float*)d_in[7];
  const float* bgd  = (const float*)d_in[8];
  const float* Wgl  = (const float*)d_in[9];
  const float* bgl  = (const float*)d_in[10];
  const float* Wgm  = (const float*)d_in[11];
  const float* bgm  = (const float*)d_in[12];
  const float* gs   = (const float*)d_in[13];
  const float* gr   = (const float*)d_in[14];
  float* out = (float*)d_out;

  const size_t NBIG = (size_t)4 * 4096 * 512;   // 8388608 elems
  char* p = (char*)d_ws;
  auto alloc_f = [&](size_t n) -> float* {
    p = (char*)(((uintptr_t)p + 255) & ~(uintptr_t)255);
    float* r = (float*)p; p += n * 4; return r;
  };
  auto alloc_s = [&](size_t n) -> unsigned short* {
    p = (char*)(((uintptr_t)p + 255) & ~(uintptr_t)255);
    unsigned short* r = (unsigned short*)p; p += n * 2; return r;
  };

  float* v       = alloc_f(NBIG);
  float* scratch = alloc_f(NBIG);
  float* W0f     = alloc_f(262144);
  float* W1f     = alloc_f(262144);   // must directly follow W0f (single memcpy)
  float* cm      = alloc_f(131072);
  float* alpha   = alloc_f(64);
  float* theta   = alloc_f(64);
  float* eta     = alloc_f(64);
  unsigned* bar  = (unsigned*)alloc_f(2048);   // hierarchical barrier: 8KB

  unsigned short* xsbH = alloc_s(NBIG);   // x_store single; reused as retH during scan
  unsigned short* xmbH = alloc_s(NBIG);   // xm single; reused as xrbH then retL
  unsigned short* xrbL = alloc_s(NBIG);
  unsigned short* qbH  = alloc_s(NBIG);
  unsigned short* qbL  = alloc_s(NBIG);
  unsigned short* kbH  = alloc_s(NBIG);
  unsigned short* kTbH = alloc_s(NBIG);   // [4][512][4096]
  unsigned short* W0bH = alloc_s(262144);
  unsigned short* W0bL = alloc_s(262144);
  unsigned short* W1bH = alloc_s(262144);
  unsigned short* W1bL = alloc_s(262144);
  unsigned short* W1TbH = alloc_s(262144);
  unsigned short* WkbH = alloc_s(262144);
  unsigned short* WvbH = alloc_s(262144);
  unsigned short* WqbH = alloc_s(262144);
  unsigned short* WqbL = alloc_s(262144);
  unsigned short* WoutbH = alloc_s(262144);
  unsigned short* WoutbL = alloc_s(262144);
  unsigned short* MTbH = alloc_s((size_t)4 * 262144);
  unsigned short* hkbH = alloc_s(131072);
  unsigned short* hkTbH = alloc_s(131072);
  unsigned short* hqbH = alloc_s(131072);
  unsigned short* hqbL = alloc_s(131072);
  unsigned short* ebH  = alloc_s(131072);
  unsigned short* eTbH = alloc_s(131072);
  unsigned short* dpTbH = alloc_s(131072);

  // ---- weight state init ----
  hipMemcpyAsync(W0f, memW, 2 * 262144 * sizeof(float), hipMemcpyDeviceToDevice, stream);
  hipMemsetAsync(bar, 0, 2048 * sizeof(unsigned), stream);
  cast_kernel<<<256, 256, 0, stream>>>(memW, W0bH, W0bL, 262144);
  cast_kernel<<<256, 256, 0, stream>>>(memW + 262144, W1bH, W1bL, 262144);
  trans_cast_kernel<<<dim3(8, 8, 1), 256, 0, stream>>>(memW + 262144, W1TbH, nullptr, 512, 512, 0, 0);
  cast_kernel<<<256, 256, 0, stream>>>(Wk, WkbH, nullptr, 262144);
  cast_kernel<<<256, 256, 0, stream>>>(Wv, WvbH, nullptr, 262144);
  cast_kernel<<<256, 256, 0, stream>>>(Wq, WqbH, WqbL, 262144);
  cast_kernel<<<256, 256, 0, stream>>>(Wout, WoutbH, WoutbL, 262144);
  trans_cast_kernel<<<dim3(8, 8, 4), 256, 0, stream>>>(Mb, MTbH, nullptr, 512, 512, 262144, 262144);

  // ---- pre-scan ----
  rms_store_kernel<<<16384, 128, 0, stream>>>(x, gs, xsbH);
  chunk_mean_kernel<<<dim3(64, 4), 128, 0, stream>>>(x, cm);
  gates_kernel<<<64, 256, 0, stream>>>(cm, Wgd, bgd, Wgl, bgl, Wgm, bgm, alpha, theta, eta);

  // GEMM grids: blockIdx.x = row-tile (multiple of 8) -> same-row blocks co-XCD.
  gemm_ss<0><<<dim3(64, 8, 4), 256, 0, stream>>>(xsbH, MTbH, 262144, xmbH);        // xm (bf16)
  gemm_ss<1><<<dim3(256, 8, 1), 256, 0, stream>>>(xmbH, WkbH, 0, scratch);         // silu(xm@Wk^T)
  l2norm_split_kernel<<<16384, 128, 0, stream>>>(scratch, kbH, nullptr);           // k
  trans_cast_kernel<<<dim3(8, 64, 4), 256, 0, stream>>>(scratch, kTbH, nullptr, 4096, 512, 2097152, 2097152); // kT
  gemm_ss<1><<<dim3(256, 8, 1), 256, 0, stream>>>(xsbH, WvbH, 0, v);               // v
  rms_retr_kernel<<<16384, 128, 0, stream>>>(x, gr, xmbH, xrbL);                   // xr split (xmbH reused)
  gemm_dd<1><<<dim3(256, 8), 256, 0, stream>>>(xmbH, xrbL, WqbH, WqbL, scratch);   // silu(xr@Wq^T)
  l2norm_split_kernel<<<16384, 128, 0, stream>>>(scratch, qbH, qbL);               // q split

  unsigned short* retH = xsbH;  // free after v-gemm
  unsigned short* retL = xmbH;  // free after q-gemm

  // ---- scan: single kernel (256 blocks x 8 waves, K-split), hierarchical barriers ----
  ScanArgs sa;
  sa.kbH = kbH; sa.qbH = qbH; sa.qbL = qbL;
  sa.W0bH = W0bH; sa.W0bL = W0bL;
  sa.hkbH = hkbH; sa.hkTbH = hkTbH;
  sa.hqbH = hqbH; sa.hqbL = hqbL;
  sa.W1bH = W1bH; sa.W1bL = W1bL;
  sa.v = v;
  sa.ebH = ebH; sa.eTbH = eTbH;
  sa.retH = retH; sa.retL = retL;
  sa.W1TbH = W1TbH; sa.dpTbH = dpTbH;
  sa.alpha = alpha; sa.theta = theta; sa.eta = eta;
  sa.kTbH = kTbH;
  sa.W0f = W0f; sa.W1f = W1f;
  sa.bar = bar;
  scan_fused<<<256, 512, 0, stream>>>(sa);

  // ---- post: out = retrieved @ Wout^T (split x split) ----
  gemm_dd<2><<<dim3(256, 8), 256, 0, stream>>>(retH, retL, WoutbH, WoutbL, out);
}

// Round 11
// 3359.198 us; speedup vs baseline: 1.1428x; 1.1428x over previous
//
#include <hip/hip_runtime.h>
#include <math.h>
#include <stdint.h>

#define D512 512
#define SC_E (2.0f / 131072.0f)

typedef __attribute__((ext_vector_type(8))) __bf16 bf16x8;
typedef __attribute__((ext_vector_type(4))) float f32x4;
#define MFMA(a,b,c) __builtin_amdgcn_mfma_f32_16x16x32_bf16(a,b,c,0,0,0)

__device__ __forceinline__ float sigmoidf_(float z){ return 1.0f/(1.0f+expf(-z)); }
__device__ __forceinline__ float siluf_(float z){ return z/(1.0f+expf(-z)); }
__device__ __forceinline__ float dsiluf_(float z){ float s=1.0f/(1.0f+expf(-z)); return s*(1.0f+z*(1.0f-s)); }

__device__ __forceinline__ unsigned short f2bf(float x){
  union { float f; unsigned u; } c; c.f = x;
  unsigned r = (c.u + 0x7fffu + ((c.u >> 16) & 1u)) >> 16;
  return (unsigned short)r;
}
__device__ __forceinline__ float bf2f(unsigned short s){
  union { unsigned u; float f; } c; c.u = ((unsigned)s) << 16; return c.f;
}
__device__ __forceinline__ void split2(float x, unsigned short& h, unsigned short& l){
  h = f2bf(x); l = f2bf(x - bf2f(h));
}
__device__ __forceinline__ bf16x8 ldf(const unsigned short* p){ return *(const bf16x8*)p; }

// ---------- write-through comm stores (agent-scope relaxed atomics -> L3) ----------
// Producers write via these; consumers use plain cached loads, made safe by ONE
// acquire-inv per scan step. No release fences / wbl2 anywhere.
__device__ __forceinline__ void stc_u32(unsigned* p, unsigned v){
  __hip_atomic_store(p, v, __ATOMIC_RELAXED, __HIP_MEMORY_SCOPE_AGENT);
}
__device__ __forceinline__ void stc_u64(unsigned long long* p, unsigned long long v){
  __hip_atomic_store(p, v, __ATOMIC_RELAXED, __HIP_MEMORY_SCOPE_AGENT);
}
__device__ __forceinline__ void stc_us4(unsigned short* p, ushort4 v){
  union { ushort4 s; unsigned long long q; } u; u.s = v;
  stc_u64((unsigned long long*)p, u.q);
}
// Pair-packed bf16 store: lanes (2c,2c+1) hold adjacent columns; even lane stores
// one u32. All call sites have even-lane elements 4B-aligned.
__device__ __forceinline__ void stc_pair(unsigned short* p, unsigned short v){
  unsigned ov = (unsigned)__shfl_xor((int)(unsigned)v, 1, 64);
  if (!(threadIdx.x & 1))
    stc_u32((unsigned*)p, ((unsigned)v) | (ov << 16));
}

// ---------- hierarchical fence-free grid barrier (256 blocks) ----------
// 8 arrival counters on separate 256B-spaced lines (group = bid&7; 32 arrivals
// each); leader (bid<8) aggregates into a global counter, publishes per-group
// 'go'; peers poll only their go line. All relaxed agent-scope; __syncthreads
// drains vmcnt so WT stores are L3-visible before arrival. Monotonic -> no ABA.
// Layout: cnt[g]=bar[g*64]; go[g]=bar[512+g*64]; global=bar[1024].
__device__ __forceinline__ void gbar_h(unsigned* bar, int grp, bool leader, unsigned p){
  __syncthreads();
  if (threadIdx.x == 0){
    unsigned* cnt = bar + grp*64;
    unsigned* go  = bar + 512 + grp*64;
    unsigned* gl  = bar + 1024;
    __hip_atomic_fetch_add(cnt, 1u, __ATOMIC_RELAXED, __HIP_MEMORY_SCOPE_AGENT);
    if (leader){
      while (__hip_atomic_load(cnt, __ATOMIC_RELAXED, __HIP_MEMORY_SCOPE_AGENT) < 32u*p)
        __builtin_amdgcn_s_sleep(1);
      __hip_atomic_fetch_add(gl, 1u, __ATOMIC_RELAXED, __HIP_MEMORY_SCOPE_AGENT);
      while (__hip_atomic_load(gl, __ATOMIC_RELAXED, __HIP_MEMORY_SCOPE_AGENT) < 8u*p)
        __builtin_amdgcn_s_sleep(1);
      __hip_atomic_store(go, p, __ATOMIC_RELAXED, __HIP_MEMORY_SCOPE_AGENT);
    } else {
      while (__hip_atomic_load(go, __ATOMIC_RELAXED, __HIP_MEMORY_SCOPE_AGENT) < p)
        __builtin_amdgcn_s_sleep(2);
    }
  }
  __syncthreads();
  __atomic_signal_fence(__ATOMIC_ACQUIRE);  // compiler-only ordering
}

// ---------- MFMA 64x64 tile primitives (4 waves; pre/post GEMMs) ----------
// Verified layouts (learn_hip m89/m91/m120).
template<int KTOT>
__device__ __forceinline__ void tile_ss(const unsigned short* __restrict__ A, int lda,
                                        const unsigned short* __restrict__ B, int ldb,
                                        f32x4* acc){
  const int lane = threadIdx.x & 63, wave = threadIdx.x >> 6;
  const int kq = (lane >> 4) << 3;
  const size_t aoff = (size_t)(wave*16 + (lane & 15)) * lda + kq;
  const size_t boff0 = (size_t)(lane & 15) * ldb + kq;
#pragma unroll
  for (int k0 = 0; k0 < KTOT; k0 += 32){
    bf16x8 av = ldf(A + aoff + k0);
#pragma unroll
    for (int nn = 0; nn < 4; nn++){
      bf16x8 bv = ldf(B + boff0 + (size_t)(nn*16)*ldb + k0);
      acc[nn] = MFMA(av, bv, acc[nn]);
    }
  }
}

template<int KTOT>
__device__ __forceinline__ void tile_dd(const unsigned short* __restrict__ Ah, const unsigned short* __restrict__ Al, int lda,
                                        const unsigned short* __restrict__ Bh, const unsigned short* __restrict__ Bl, int ldb,
                                        f32x4* acc){
  const int lane = threadIdx.x & 63, wave = threadIdx.x >> 6;
  const int kq = (lane >> 4) << 3;
  const size_t aoff = (size_t)(wave*16 + (lane & 15)) * lda + kq;
  const size_t boff0 = (size_t)(lane & 15) * ldb + kq;
#pragma unroll
  for (int k0 = 0; k0 < KTOT; k0 += 32){
    bf16x8 ah = ldf(Ah + aoff + k0);
    bf16x8 al = ldf(Al + aoff + k0);
#pragma unroll
    for (int nn = 0; nn < 4; nn++){
      const size_t bo = boff0 + (size_t)(nn*16)*ldb + k0;
      bf16x8 bh = ldf(Bh + bo);
      bf16x8 bl = ldf(Bl + bo);
      acc[nn] = MFMA(ah, bh, acc[nn]);
      acc[nn] = MFMA(ah, bl, acc[nn]);
      acc[nn] = MFMA(al, bh, acc[nn]);
    }
  }
}

// ---------- sliced tile primitives (scan): 16 A-rows x 64 B-rows, 1 f32x4/thread ----------
// Out: A_row = (lane>>4)*4 + r, B_col = wave*16 + (lane&15).
template<int KTOT>
__device__ __forceinline__ void slice_ss(const unsigned short* __restrict__ A16, int lda,
                                         const unsigned short* __restrict__ B64, int ldb,
                                         f32x4& acc){
  const int lane = threadIdx.x & 63, wave = threadIdx.x >> 6;
  const int kq = (lane >> 4) << 3;
  const size_t aoff = (size_t)(lane & 15) * lda + kq;
  const size_t boff = (size_t)(wave*16 + (lane & 15)) * ldb + kq;
#pragma unroll
  for (int k0 = 0; k0 < KTOT; k0 += 32){
    bf16x8 av = ldf(A16 + aoff + k0);
    bf16x8 bv = ldf(B64 + boff + k0);
    acc = MFMA(av, bv, acc);
  }
}

template<int KTOT>
__device__ __forceinline__ void slice_dd(const unsigned short* __restrict__ Ah, const unsigned short* __restrict__ Al, int lda,
                                         const unsigned short* __restrict__ Bh, const unsigned short* __restrict__ Bl, int ldb,
                                         f32x4& acc){
  const int lane = threadIdx.x & 63, wave = threadIdx.x >> 6;
  const int kq = (lane >> 4) << 3;
  const size_t aoff = (size_t)(lane & 15) * lda + kq;
  const size_t boff = (size_t)(wave*16 + (lane & 15)) * ldb + kq;
#pragma unroll
  for (int k0 = 0; k0 < KTOT; k0 += 32){
    bf16x8 ah = ldf(Ah + aoff + k0);
    bf16x8 al = ldf(Al + aoff + k0);
    bf16x8 bh = ldf(Bh + boff + k0);
    bf16x8 bl = ldf(Bl + boff + k0);
    acc = MFMA(ah, bh, acc);
    acc = MFMA(ah, bl, acc);
    acc = MFMA(al, bh, acc);
  }
}

// ---------- elementwise / pre kernels ----------
__global__ void rms_store_kernel(const float* __restrict__ x, const float* __restrict__ g,
                                 unsigned short* __restrict__ dstH){
  const size_t row = blockIdx.x; const int tid = threadIdx.x; // 128 thr
  const float4 xv = *(const float4*)(x + row * D512 + tid * 4);
  float ss = xv.x*xv.x + xv.y*xv.y + xv.z*xv.z + xv.w*xv.w;
  for (int o = 32; o > 0; o >>= 1) ss += __shfl_xor(ss, o, 64);
  __shared__ float w2[2];
  if ((tid & 63) == 0) w2[tid >> 6] = ss;
  __syncthreads();
  const float r = rsqrtf((w2[0] + w2[1]) * (1.0f / 512.0f) + 1.1920929e-07f);
  const float4 gv = *(const float4*)(g + tid * 4);
  ushort4 h;
  h.x = f2bf(xv.x*r*gv.x); h.y = f2bf(xv.y*r*gv.y); h.z = f2bf(xv.z*r*gv.z); h.w = f2bf(xv.w*r*gv.w);
  *(ushort4*)(dstH + row * D512 + tid * 4) = h;
}

__global__ void rms_retr_kernel(const float* __restrict__ x, const float* __restrict__ g,
                                unsigned short* __restrict__ dstH, unsigned short* __restrict__ dstL){
  const size_t row = blockIdx.x; const int tid = threadIdx.x; // 128 thr
  const float4 xv = *(const float4*)(x + row * D512 + tid * 4);
  float ss = xv.x*xv.x + xv.y*xv.y + xv.z*xv.z + xv.w*xv.w;
  for (int o = 32; o > 0; o >>= 1) ss += __shfl_xor(ss, o, 64);
  __shared__ float w2[2];
  if ((tid & 63) == 0) w2[tid >> 6] = ss;
  __syncthreads();
  const float r = rsqrtf((w2[0] + w2[1]) * (1.0f / 512.0f) + 1.1920929e-07f);
  const float4 gv = *(const float4*)(g + tid * 4);
  float v0 = xv.x*r*gv.x, v1 = xv.y*r*gv.y, v2 = xv.z*r*gv.z, v3 = xv.w*r*gv.w;
  ushort4 h, l;
  split2(v0, h.x, l.x); split2(v1, h.y, l.y); split2(v2, h.z, l.z); split2(v3, h.w, l.w);
  *(ushort4*)(dstH + row * D512 + tid * 4) = h;
  *(ushort4*)(dstL + row * D512 + tid * 4) = l;
}

// fp32 writeback only when dstL == nullptr (k path: trans_cast re-reads buf).
// q path (dstL != nullptr) never re-reads buf -> skip the 32MB dead store.
__global__ void l2norm_split_kernel(float* __restrict__ buf,
                                    unsigned short* __restrict__ dstH, unsigned short* __restrict__ dstL){
  const size_t row = blockIdx.x; const int tid = threadIdx.x; // 128 thr
  float4 xv = *(const float4*)(buf + row * D512 + tid * 4);
  float ss = xv.x*xv.x + xv.y*xv.y + xv.z*xv.z + xv.w*xv.w;
  for (int o = 32; o > 0; o >>= 1) ss += __shfl_xor(ss, o, 64);
  __shared__ float w2[2];
  if ((tid & 63) == 0) w2[tid >> 6] = ss;
  __syncthreads();
  const float n = sqrtf(w2[0] + w2[1]);
  const float sc = 1.0f / fmaxf(n, 1e-12f);
  xv.x *= sc; xv.y *= sc; xv.z *= sc; xv.w *= sc;
  ushort4 h; h.x = f2bf(xv.x); h.y = f2bf(xv.y); h.z = f2bf(xv.z); h.w = f2bf(xv.w);
  *(ushort4*)(dstH + row * D512 + tid * 4) = h;
  if (dstL){
    ushort4 l;
    l.x = f2bf(xv.x - bf2f(h.x)); l.y = f2bf(xv.y - bf2f(h.y));
    l.z = f2bf(xv.z - bf2f(h.z)); l.w = f2bf(xv.w - bf2f(h.w));
    *(ushort4*)(dstL + row * D512 + tid * 4) = l;
  } else {
    *(float4*)(buf + row * D512 + tid * 4) = xv;
  }
}

__global__ void cast_kernel(const float* __restrict__ src, unsigned short* __restrict__ dstH,
                            unsigned short* __restrict__ dstL, int n){
  int i = (blockIdx.x * 256 + threadIdx.x) * 4;
  if (i >= n) return;
  float4 v = *(const float4*)(src + i);
  ushort4 h; h.x = f2bf(v.x); h.y = f2bf(v.y); h.z = f2bf(v.z); h.w = f2bf(v.w);
  *(ushort4*)(dstH + i) = h;
  if (dstL){
    ushort4 l;
    l.x = f2bf(v.x - bf2f(h.x)); l.y = f2bf(v.y - bf2f(h.y));
    l.z = f2bf(v.z - bf2f(h.z)); l.w = f2bf(v.w - bf2f(h.w));
    *(ushort4*)(dstL + i) = l;
  }
}

// transpose fp32 [R][C] -> bf16 (single/split) [C][R]; grid(C/64, R/64, batches)
__global__ void trans_cast_kernel(const float* __restrict__ src, unsigned short* __restrict__ dstH,
                                  unsigned short* __restrict__ dstL, int R, int C,
                                  size_t sbs, size_t dbs){
  __shared__ float t[64][65];
  const int b = blockIdx.z;
  const float* s = src + (size_t)b * sbs;
  const int r0 = blockIdx.y * 64, c0 = blockIdx.x * 64;
  for (int i = threadIdx.x; i < 4096; i += 256){
    int rr = i >> 6, cc = i & 63;
    t[rr][cc] = s[(size_t)(r0 + rr) * C + c0 + cc];
  }
  __syncthreads();
  for (int i = threadIdx.x; i < 4096; i += 256){
    int cc = i >> 6, rr = i & 63;
    float v = t[rr][cc];
    size_t off = (size_t)b * dbs + (size_t)(c0 + cc) * R + r0 + rr;
    unsigned short h = f2bf(v);
    dstH[off] = h;
    if (dstL) dstL[off] = f2bf(v - bf2f(h));
  }
}

__global__ void chunk_mean_kernel(const float* __restrict__ x, float* __restrict__ cm){
  const int c = blockIdx.x, b = blockIdx.y, tid = threadIdx.x; // 128 threads
  const float* base = x + ((size_t)b * 4096 + (size_t)c * 64) * D512 + tid * 4;
  float4 s = {0,0,0,0};
  for (int r = 0; r < 64; r++){
    const float4 v = *(const float4*)(base + (size_t)r * D512);
    s.x += v.x; s.y += v.y; s.z += v.z; s.w += v.w;
  }
  const float inv = 1.0f / 64.0f;
  s.x *= inv; s.y *= inv; s.z *= inv; s.w *= inv;
  *(float4*)(cm + ((size_t)b * 64 + c) * D512 + tid * 4) = s;
}

// gates: single pass over the 3 gate matrices (all 4 batch chunk-means staged in
// LDS) -- the 4-pass version re-read 3MB of weights per batch (4x amplification).
__global__ void gates_kernel(const float* __restrict__ cm,
                             const float* __restrict__ Wgd, const float* __restrict__ bgd,
                             const float* __restrict__ Wgl, const float* __restrict__ bgl,
                             const float* __restrict__ Wgm, const float* __restrict__ bgm,
                             float* __restrict__ alpha, float* __restrict__ theta, float* __restrict__ eta){
  const int c = blockIdx.x, tid = threadIdx.x; // 256 threads
  __shared__ float cmsh[4][512];
#pragma unroll
  for (int b = 0; b < 4; b++)
    if (tid < 128)
      *(float4*)&cmsh[b][tid * 4] = *(const float4*)(cm + ((size_t)b * 64 + c) * D512 + tid * 4);
  __syncthreads();
  float s0 = 0.f, s1 = 0.f, s2 = 0.f;
  for (int j = tid; j < 512; j += 256){
    float d0[4], d1[4], d2[4];
#pragma unroll
    for (int b = 0; b < 4; b++){ d0[b] = bgd[j]; d1[b] = bgl[j]; d2[b] = bgm[j]; }
    const float* w0 = Wgd + (size_t)j * D512;
    const float* w1 = Wgl + (size_t)j * D512;
    const float* w2 = Wgm + (size_t)j * D512;
    for (int kk = 0; kk < 512; kk += 4){
      const float4 a = *(const float4*)(w0 + kk);
      const float4 e = *(const float4*)(w1 + kk);
      const float4 g = *(const float4*)(w2 + kk);
#pragma unroll
      for (int b = 0; b < 4; b++){
        const float4 cv = *(const float4*)&cmsh[b][kk];
        d0[b] += cv.x*a.x + cv.y*a.y + cv.z*a.z + cv.w*a.w;
        d1[b] += cv.x*e.x + cv.y*e.y + cv.z*e.z + cv.w*e.w;
        d2[b] += cv.x*g.x + cv.y*g.y + cv.z*g.z + cv.w*g.w;
      }
    }
#pragma unroll
    for (int b = 0; b < 4; b++){
      s0 += sigmoidf_(d0[b]); s1 += sigmoidf_(d1[b]); s2 += sigmoidf_(d2[b]);
    }
  }
  __shared__ float red[256];
  const float inv = 1.0f / 2048.0f;
  red[tid] = s0; __syncthreads();
  for (int o = 128; o > 0; o >>= 1){ if (tid < o) red[tid] += red[tid + o]; __syncthreads(); }
  if (tid == 0) alpha[c] = red[0] * inv * 0.01f;
  __syncthreads();
  red[tid] = s1; __syncthreads();
  for (int o = 128; o > 0; o >>= 1){ if (tid < o) red[tid] += red[tid + o]; __syncthreads(); }
  if (tid == 0) theta[c] = red[0] * inv * 0.1f;
  __syncthreads();
  red[tid] = s2; __syncthreads();
  for (int o = 128; o > 0; o >>= 1){ if (tid < o) red[tid] += red[tid + o]; __syncthreads(); }
  if (tid == 0) eta[c] = red[0] * inv * 0.9f;
}

// ---------- big MFMA GEMMs (NT: C[i,j] = sum_k A[i,k] B[j,k]) ----------
// blockIdx.x = ROW tile (multiple of 8) -> same-A-panel blocks co-XCD.
template<int MODE>
__global__ __launch_bounds__(256) void gemm_ss(const unsigned short* __restrict__ A,
                                               const unsigned short* __restrict__ B, size_t bzs,
                                               void* __restrict__ out){
  const int lane = threadIdx.x & 63, wave = threadIdx.x >> 6;
  const int er = wave*16 + ((lane >> 4) << 2), ec = lane & 15;
  const size_t row0 = (size_t)blockIdx.z * 4096 + (size_t)blockIdx.x * 64;
  const int n0 = blockIdx.y * 64;
  f32x4 acc[4] = {};
  tile_ss<512>(A + row0 * D512, D512, B + (size_t)blockIdx.z * bzs + (size_t)n0 * D512, D512, acc);
#pragma unroll
  for (int nn = 0; nn < 4; nn++)
#pragma unroll
    for (int r = 0; r < 4; r++){
      const size_t off = (row0 + er + r) * D512 + n0 + nn*16 + ec;
      float val = acc[nn][r];
      if (MODE == 0) ((unsigned short*)out)[off] = f2bf(val);
      else if (MODE == 1) ((float*)out)[off] = siluf_(val);
      else ((float*)out)[off] = val;
    }
}

template<int MODE>
__global__ __launch_bounds__(256) void gemm_dd(const unsigned short* __restrict__ Ah, const unsigned short* __restrict__ Al,
                                               const unsigned short* __restrict__ Bh, const unsigned short* __restrict__ Bl,
                                               float* __restrict__ out){
  const int lane = threadIdx.x & 63, wave = threadIdx.x >> 6;
  const int er = wave*16 + ((lane >> 4) << 2), ec = lane & 15;
  const size_t row0 = (size_t)blockIdx.x * 64;
  const int n0 = blockIdx.y * 64;
  f32x4 acc[4] = {};
  tile_dd<512>(Ah + row0 * D512, Al + row0 * D512, D512,
               Bh + (size_t)n0 * D512, Bl + (size_t)n0 * D512, D512, acc);
#pragma unroll
  for (int nn = 0; nn < 4; nn++)
#pragma unroll
    for (int r = 0; r < 4; r++){
      const size_t off = (row0 + er + r) * D512 + n0 + nn*16 + ec;
      out[off] = (MODE == 1) ? siluf_(acc[nn][r]) : acc[nn][r];
    }
}

// ---------- fused scan (r9-proven config: 256 blocks x 256 thr, lockstep) ----------
// Grid = 256 blocks: bid = s*64 + T (T = tile 0..63, s = 16-row slice 0..3).
// Comm buffers: WT stores + cached reads + one acquire-inv per step.
// Optimizer state (W0,W1,mom0,mom1): REGISTERS of the owning D-block (16 f32/thr).
// spT: register float4 carried A->C within the same block & iteration.
// Occupancy lessons: r8 (fewer CUs) and r10 (K-split, 2 waves/SIMD) both LOST to
// this 1-wave/SIMD all-256-CU lockstep config -- do not revisit.
struct ScanArgs {
  const unsigned short* kbH;
  const unsigned short* qbH; const unsigned short* qbL;
  unsigned short* W0bH; unsigned short* W0bL;
  unsigned short* hkbH; unsigned short* hkTbH;
  unsigned short* hqbH; unsigned short* hqbL;
  unsigned short* W1bH; unsigned short* W1bL;
  const float* v;
  unsigned short* ebH; unsigned short* eTbH;
  unsigned short* retH; unsigned short* retL;
  unsigned short* W1TbH; unsigned short* dpTbH;
  const float* alpha; const float* theta; const float* eta;
  const unsigned short* kTbH;
  const float* W0f; const float* W1f;
  unsigned* bar;
};

__global__ __launch_bounds__(256, 2) void scan_fused(ScanArgs P){
  const int bid = blockIdx.x;
  const int s = bid >> 6;
  const int T = bid & 63;
  const int grp = bid & 7;
  const bool leader = (bid < 8);
  const int lane = threadIdx.x & 63, wave = threadIdx.x >> 6;
  const int ar = (lane >> 4) << 2;           // A-row base within 16-slice
  const int bc = wave*16 + (lane & 15);      // B-col within 64
  const int kq = (lane >> 4) << 3;

  // ---- D-role register state: W0/W1 tile rows jx*64+s*16+ar+r, cols dx*64+bc ----
  const int jx = T >> 3, dx = T & 7;
  f32x4 w0r = {}, m0r = {}, w1r = {}, m1r = {};
  const size_t woff = (size_t)(jx*64 + s*16 + ar) * D512 + dx*64 + bc;
#pragma unroll
  for (int r = 0; r < 4; r++){
    w0r[r] = P.W0f[woff + (size_t)r * D512];
    w1r[r] = P.W1f[woff + (size_t)r * D512];
  }

  unsigned p = 0;
  for (int t = 0; t < 64; ++t){
    float4 sp = {0,0,0,0};   // a12 -> c1 carry (same block, same thread mapping)

    // ---------------- phase A ----------------
    if (T < 32){
      // a12 (tile ib,jxa): hk[i][j], hkT[j][i], sp regs
      const int ib = T >> 3, jxa = T & 7;
      f32x4 acc = {};
      slice_ss<512>(P.kbH + ((size_t)ib*4096 + (size_t)t*64 + s*16) * D512, D512,
                    P.W0bH + (size_t)jxa*64 * D512, D512, acc);
      const int i0 = ib*64 + s*16 + ar;
      const int j  = jxa*64 + bc;
      ushort4 hv;
#pragma unroll
      for (int r = 0; r < 4; r++){
        const float pfull = acc[r];
        const unsigned short hb = f2bf(siluf_(pfull));
        stc_pair(&P.hkbH[(size_t)(i0 + r) * D512 + j], hb);
        ((unsigned short*)&hv)[r] = hb;
        ((float*)&sp)[r] = dsiluf_(pfull);
      }
      stc_us4(&P.hkTbH[(size_t)j * 256 + i0], hv);
    } else {
      // a3 (tile bt,nx): hq split
      const int u = T - 32, bt = u >> 3, nx = u & 7;
      const size_t ab = ((size_t)bt*4096 + (size_t)t*64 + s*16) * D512;
      f32x4 acc = {};
      slice_dd<512>(P.qbH + ab, P.qbL + ab, D512,
                    P.W0bH + (size_t)nx*64 * D512, P.W0bL + (size_t)nx*64 * D512, D512, acc);
      const int i0 = bt*64 + s*16 + ar;
      const int j  = nx*64 + bc;
#pragma unroll
      for (int r = 0; r < 4; r++){
        const float h = siluf_(acc[r]);
        unsigned short hh, ll; split2(h, hh, ll);
        stc_pair(&P.hqbH[(size_t)(i0 + r) * D512 + j], hh);
        stc_pair(&P.hqbL[(size_t)(i0 + r) * D512 + j], ll);
      }
    }
    ++p; gbar_h(P.bar, grp, leader, p);

    // ---------------- phase B ----------------
    if (T < 32){
      // b12 (tile ib,nx): e[i][m], eT[m][i]
      const int ib = T >> 3, nx = T & 7;
      f32x4 acc = {};
      slice_ss<512>(P.hkbH + (size_t)(ib*64 + s*16) * D512, D512,
                    P.W1bH + (size_t)nx*64 * D512, D512, acc);
      const int i0 = ib*64 + s*16 + ar;
      const int m  = nx*64 + bc;
      ushort4 ev;
#pragma unroll
      for (int r = 0; r < 4; r++){
        const size_t grow = (size_t)ib*4096 + (size_t)t*64 + s*16 + ar + r;
        const float vv = P.v[grow * D512 + m];
        const unsigned short eb = f2bf((acc[r] - vv) * SC_E);
        stc_pair(&P.ebH[(size_t)(i0 + r) * D512 + m], eb);
        ((unsigned short*)&ev)[r] = eb;
      }
      stc_us4(&P.eTbH[(size_t)m * 256 + i0], ev);
    } else {
      // b3 (tile bt,nx): ret split (plain cached stores; consumed post-scan)
      const int u = T - 32, bt = u >> 3, nx = u & 7;
      const size_t ab = (size_t)(bt*64 + s*16) * D512;
      f32x4 acc = {};
      slice_dd<512>(P.hqbH + ab, P.hqbL + ab, D512,
                    P.W1bH + (size_t)nx*64 * D512, P.W1bL + (size_t)nx*64 * D512, D512, acc);
#pragma unroll
      for (int r = 0; r < 4; r++){
        const size_t grow = (size_t)bt*4096 + (size_t)t*64 + s*16 + ar + r;
        unsigned short hh, ll; split2(acc[r], hh, ll);
        const size_t off = grow * D512 + nx*64 + bc;
        P.retH[off] = hh; P.retL[off] = ll;
      }
    }
    ++p; gbar_h(P.bar, grp, leader, p);

    // ---------------- phase C (c1 only; mom1 folded into D) ----------------
    if (T < 32){
      const int ib = T >> 3, jxa = T & 7;
      f32x4 acc = {};
      slice_ss<512>(P.ebH + (size_t)(ib*64 + s*16) * D512, D512,
                    P.W1TbH + (size_t)jxa*64 * D512, D512, acc);
      const int i0 = ib*64 + s*16 + ar;
      const int j  = jxa*64 + bc;
      ushort4 dv;
#pragma unroll
      for (int r = 0; r < 4; r++)
        ((unsigned short*)&dv)[r] = f2bf(acc[r] * ((const float*)&sp)[r]);
      stc_us4(&P.dpTbH[(size_t)j * 256 + i0], dv);
    }
    ++p; gbar_h(P.bar, grp, leader, p);

    // ---------------- phase D ----------------
    {
      // gW0 = dpT @ kT (K=256)
      f32x4 g0 = {};
      const unsigned short* A16 = P.dpTbH + (size_t)(jx*64 + s*16) * 256;
      const size_t aoff = (size_t)(lane & 15) * 256 + kq;
      const size_t brow = (size_t)(dx*64 + bc) * 4096;
#pragma unroll
      for (int k0 = 0; k0 < 256; k0 += 32){
        bf16x8 av = ldf(A16 + aoff + k0);
        const int pl = k0 >> 6;
        bf16x8 bv = ldf(P.kTbH + (size_t)pl * (512*4096) + brow + (size_t)t*64 + (k0 & 63) + kq);
        g0 = MFMA(av, bv, g0);
      }
      // gW1 tile: rows m=jx*64+s*16+ar+r, cols j=dx*64+bc, K=256
      f32x4 g1 = {};
      slice_ss<256>(P.eTbH + (size_t)(jx*64 + s*16) * 256, 256,
                    P.hkTbH + (size_t)(dx*64) * 256, 256, g1);
      const float al = P.alpha[t], th = P.theta[t], et = P.eta[t];
      ushort4 tv;
#pragma unroll
      for (int r = 0; r < 4; r++){
        const size_t off = woff + (size_t)r * D512;
        m0r[r] = et * m0r[r] - th * g0[r];
        w0r[r] = (1.0f - al) * w0r[r] + m0r[r];
        unsigned short hh, ll; split2(w0r[r], hh, ll);
        stc_pair(&P.W0bH[off], hh); stc_pair(&P.W0bL[off], ll);
        m1r[r] = et * m1r[r] - th * g1[r];
        w1r[r] = (1.0f - al) * w1r[r] + m1r[r];
        unsigned short h1, l1; split2(w1r[r], h1, l1);
        stc_pair(&P.W1bH[off], h1); stc_pair(&P.W1bL[off], l1);
        ((unsigned short*)&tv)[r] = h1;
      }
      // W1T[j][m0..m0+4) : contiguous u64 per thread
      stc_us4(&P.W1TbH[(size_t)(dx*64 + bc) * D512 + jx*64 + s*16 + ar], tv);
    }
    ++p; gbar_h(P.bar, grp, leader, p);

    // One invalidate per step: all of step t's WT writes become safely readable
    // via plain cached loads throughout step t+1.
    __builtin_amdgcn_fence(__ATOMIC_ACQUIRE, "agent");
  }
}

// ---------------- launcher ----------------
extern "C" void kernel_launch(void* const* d_in, const int* in_sizes, int n_in,
                              void* d_out, int out_size, void* d_ws, size_t ws_size,
                              hipStream_t stream) {
  const float* x    = (const float*)d_in[0];
  const float* Mb   = (const float*)d_in[1];
  const float* memW = (const float*)d_in[2];
  const float* Wk   = (const float*)d_in[3];
  const float* Wv   = (const float*)d_in[4];
  const float* Wq   = (const float*)d_in[5];
  const float* Wout = (const float*)d_in[6];
  const float* Wgd  = (const float*)d_in[7];
  const float* bgd  = (const float*)d_in[8];
  const float* Wgl  = (const float*)d_in[9];
  const float* bgl  = (const float*)d_in[10];
  const float* Wgm  = (const float*)d_in[11];
  const float* bgm  = (const float*)d_in[12];
  const float* gs   = (const float*)d_in[13];
  const float* gr   = (const float*)d_in[14];
  float* out = (float*)d_out;

  const size_t NBIG = (size_t)4 * 4096 * 512;   // 8388608 elems
  char* p = (char*)d_ws;
  auto alloc_f = [&](size_t n) -> float* {
    p = (char*)(((uintptr_t)p + 255) & ~(uintptr_t)255);
    float* r = (float*)p; p += n * 4; return r;
  };
  auto alloc_s = [&](size_t n) -> unsigned short* {
    p = (char*)(((uintptr_t)p + 255) & ~(uintptr_t)255);
    unsigned short* r = (unsigned short*)p; p += n * 2; return r;
  };

  float* v       = alloc_f(NBIG);
  float* scratch = alloc_f(NBIG);
  float* W0f     = alloc_f(262144);
  float* W1f     = alloc_f(262144);   // must directly follow W0f (single memcpy)
  float* cm      = alloc_f(131072);
  float* alpha   = alloc_f(64);
  float* theta   = alloc_f(64);
  float* eta     = alloc_f(64);
  unsigned* bar  = (unsigned*)alloc_f(2048);   // hierarchical barrier: 8KB

  unsigned short* xsbH = alloc_s(NBIG);   // x_store single; reused as retH during scan
  unsigned short* xmbH = alloc_s(NBIG);   // xm single; reused as xrbH then retL
  unsigned short* xrbL = alloc_s(NBIG);
  unsigned short* qbH  = alloc_s(NBIG);
  unsigned short* qbL  = alloc_s(NBIG);
  unsigned short* kbH  = alloc_s(NBIG);
  unsigned short* kTbH = alloc_s(NBIG);   // [4][512][4096]
  unsigned short* W0bH = alloc_s(262144);
  unsigned short* W0bL = alloc_s(262144);
  unsigned short* W1bH = alloc_s(262144);
  unsigned short* W1bL = alloc_s(262144);
  unsigned short* W1TbH = alloc_s(262144);
  unsigned short* WkbH = alloc_s(262144);
  unsigned short* WvbH = alloc_s(262144);
  unsigned short* WqbH = alloc_s(262144);
  unsigned short* WqbL = alloc_s(262144);
  unsigned short* WoutbH = alloc_s(262144);
  unsigned short* WoutbL = alloc_s(262144);
  unsigned short* MTbH = alloc_s((size_t)4 * 262144);
  unsigned short* hkbH = alloc_s(131072);
  unsigned short* hkTbH = alloc_s(131072);
  unsigned short* hqbH = alloc_s(131072);
  unsigned short* hqbL = alloc_s(131072);
  unsigned short* ebH  = alloc_s(131072);
  unsigned short* eTbH = alloc_s(131072);
  unsigned short* dpTbH = alloc_s(131072);

  // ---- weight state init ----
  hipMemcpyAsync(W0f, memW, 2 * 262144 * sizeof(float), hipMemcpyDeviceToDevice, stream);
  hipMemsetAsync(bar, 0, 2048 * sizeof(unsigned), stream);
  cast_kernel<<<256, 256, 0, stream>>>(memW, W0bH, W0bL, 262144);
  cast_kernel<<<256, 256, 0, stream>>>(memW + 262144, W1bH, W1bL, 262144);
  trans_cast_kernel<<<dim3(8, 8, 1), 256, 0, stream>>>(memW + 262144, W1TbH, nullptr, 512, 512, 0, 0);
  cast_kernel<<<256, 256, 0, stream>>>(Wk, WkbH, nullptr, 262144);
  cast_kernel<<<256, 256, 0, stream>>>(Wv, WvbH, nullptr, 262144);
  cast_kernel<<<256, 256, 0, stream>>>(Wq, WqbH, WqbL, 262144);
  cast_kernel<<<256, 256, 0, stream>>>(Wout, WoutbH, WoutbL, 262144);
  trans_cast_kernel<<<dim3(8, 8, 4), 256, 0, stream>>>(Mb, MTbH, nullptr, 512, 512, 262144, 262144);

  // ---- pre-scan ----
  rms_store_kernel<<<16384, 128, 0, stream>>>(x, gs, xsbH);
  chunk_mean_kernel<<<dim3(64, 4), 128, 0, stream>>>(x, cm);
  gates_kernel<<<64, 256, 0, stream>>>(cm, Wgd, bgd, Wgl, bgl, Wgm, bgm, alpha, theta, eta);

  // GEMM grids: blockIdx.x = row-tile (multiple of 8) -> same-row blocks co-XCD.
  gemm_ss<0><<<dim3(64, 8, 4), 256, 0, stream>>>(xsbH, MTbH, 262144, xmbH);        // xm (bf16)
  gemm_ss<1><<<dim3(256, 8, 1), 256, 0, stream>>>(xmbH, WkbH, 0, scratch);         // silu(xm@Wk^T)
  l2norm_split_kernel<<<16384, 128, 0, stream>>>(scratch, kbH, nullptr);           // k (+fp32 wb for kT)
  trans_cast_kernel<<<dim3(8, 64, 4), 256, 0, stream>>>(scratch, kTbH, nullptr, 4096, 512, 2097152, 2097152); // kT
  gemm_ss<1><<<dim3(256, 8, 1), 256, 0, stream>>>(xsbH, WvbH, 0, v);               // v
  rms_retr_kernel<<<16384, 128, 0, stream>>>(x, gr, xmbH, xrbL);                   // xr split (xmbH reused)
  gemm_dd<1><<<dim3(256, 8), 256, 0, stream>>>(xmbH, xrbL, WqbH, WqbL, scratch);   // silu(xr@Wq^T)
  l2norm_split_kernel<<<16384, 128, 0, stream>>>(scratch, qbH, qbL);               // q split (no fp32 wb)

  unsigned short* retH = xsbH;  // free after v-gemm
  unsigned short* retL = xmbH;  // free after q-gemm

  // ---- scan: single kernel, hierarchical arrival barriers + one inv per step ----
  ScanArgs sa;
  sa.kbH = kbH; sa.qbH = qbH; sa.qbL = qbL;
  sa.W0bH = W0bH; sa.W0bL = W0bL;
  sa.hkbH = hkbH; sa.hkTbH = hkTbH;
  sa.hqbH = hqbH; sa.hqbL = hqbL;
  sa.W1bH = W1bH; sa.W1bL = W1bL;
  sa.v = v;
  sa.ebH = ebH; sa.eTbH = eTbH;
  sa.retH = retH; sa.retL = retL;
  sa.W1TbH = W1TbH; sa.dpTbH = dpTbH;
  sa.alpha = alpha; sa.theta = theta; sa.eta = eta;
  sa.kTbH = kTbH;
  sa.W0f = W0f; sa.W1f = W1f;
  sa.bar = bar;
  scan_fused<<<256, 256, 0, stream>>>(sa);

  // ---- post: out = retrieved @ Wout^T (split x split) ----
  gemm_dd<2><<<dim3(256, 8), 256, 0, stream>>>(retH, retL, WoutbH, WoutbL, out);
}